// Round 10
// baseline (529.884 us; speedup 1.0000x reference)
//
#include <hip/hip_runtime.h>
#include <cstdint>

// GRU (B=128, T=128, I=12, H=512) persistent kernel, round 10.
// 256 WGs = 8 batch-groups (16 rows) x 32 col-groups (16 h-cols), 1 WG/CU.
// W_hh chunk LDS-resident in MFMA fragment order (bf16 hi/lo x3 MFMA).
// Base = round 9 (524us): self-tagged exchange (u32 = hi16|lo14|tag2), sc1,
// raw barriers (no vmem drains).
// Round-10: TWO-CHAIN INTERLEAVE. Rows split into chain A (rows 0-7/bg-block)
// and chain B (rows 8-15), alternated within each step:
//   pollA/stageA -> bar -> GEMM -> bar -> gatesA/publishA ->
//   pollB/stageB -> bar -> GEMM -> bar -> gatesB/publishB
// A's publish->visibility fabric round trip propagates during B's half (and
// vice-versa), so each poll usually detects on the first sweep. Tag induction
// per chain identical to r7/r9 (disjoint rows, same slot cycle). x_l is
// double-buffered by t&1 (removes the trailing barrier).

typedef __attribute__((ext_vector_type(4))) float f32x4;
typedef __attribute__((ext_vector_type(8))) __bf16 bf16x8;

#define NTHREADS 256
#define CG_N 32
#define BB 16
#define BBH 8
#define HC 16
#define T_STEPS 128
#define I_DIM 12
#define H_DIM 512

// ws byte offsets
#define WS_HX0   0         // hx[0]: [128][512] u32   256 KB
#define WS_HX1   262144    // hx[1]                   256 KB
#define WS_FLAGS 524288    // [8 bg][32 consumer][32 producer] u32 (init barrier only)

__device__ __forceinline__ float bf16f(unsigned short u){
  return __uint_as_float(((unsigned int)u) << 16);
}
__device__ __forceinline__ void split_bf16(float x, unsigned short &hi, unsigned short &lo){
  unsigned int u = __float_as_uint(x);
  hi = (unsigned short)(u >> 16);
  float r = x - __uint_as_float((u >> 16) << 16);   // exact residual
  unsigned int ru = __float_as_uint(r);
  ru += 0x7fffu + ((ru >> 16) & 1u);                // RNE to bf16
  lo = (unsigned short)(ru >> 16);
}
__device__ __forceinline__ float fsigmoid(float x){ return 1.0f / (1.0f + __expf(-x)); }
__device__ __forceinline__ float ftanh(float x){ return 2.0f / (1.0f + __expf(-2.0f * x)) - 1.0f; }
__device__ __forceinline__ f32x4 MFMA(bf16x8 a, bf16x8 b, f32x4 c){
  return __builtin_amdgcn_mfma_f32_16x16x32_bf16(a, b, c, 0, 0, 0);
}
__device__ __forceinline__ void wait_vm0(){
  asm volatile("s_waitcnt vmcnt(0)" ::: "memory");
}
__device__ __forceinline__ unsigned int hiP(unsigned int x, unsigned int y){
  return (x >> 16) | (y & 0xFFFF0000u);
}
__device__ __forceinline__ unsigned int loP(unsigned int x, unsigned int y){
  return (x & 0xFFFFu) | (y << 16);
}

// raw barriers: sched_barrier fences pin ordering; no vmem drain
__device__ __forceinline__ void bar_lgkm(){
  asm volatile("s_waitcnt lgkmcnt(0)" ::: "memory");
  __builtin_amdgcn_sched_barrier(0);
  __builtin_amdgcn_s_barrier();
  __builtin_amdgcn_sched_barrier(0);
}

// sc1 (device-scope) primitives — proven exchange path
__device__ __forceinline__ void dev_store_u32(unsigned int* p, unsigned int v){
  asm volatile("global_store_dword %0, %1, off sc1" :: "v"(p), "v"(v) : "memory");
}
__device__ __forceinline__ unsigned int dev_load_u32(const unsigned int* p){
  unsigned int v;
  asm volatile("global_load_dword %0, %1, off sc1\n\ts_waitcnt vmcnt(0)"
               : "=v"(v) : "v"(p) : "memory");
  return v;
}
__device__ __forceinline__ uint4 load4_sc1(const unsigned int* p){
  uint4 v;
  asm volatile("global_load_dwordx4 %0, %1, off sc1" : "=v"(v) : "v"(p) : "memory");
  return v;
}
// one sweep of 4 chunks (16 u32) + single waitcnt
__device__ __forceinline__ void load_h4(const unsigned int* p, uint4* pr){
  uint4 v0, v1, v2, v3;
  asm volatile(
    "global_load_dwordx4 %0, %4, off sc1\n\t"
    "global_load_dwordx4 %1, %4, off offset:16 sc1\n\t"
    "global_load_dwordx4 %2, %4, off offset:32 sc1\n\t"
    "global_load_dwordx4 %3, %4, off offset:48 sc1\n\t"
    "s_waitcnt vmcnt(0)"
    : "=&v"(v0), "=&v"(v1), "=&v"(v2), "=&v"(v3)
    : "v"(p) : "memory");
  pr[0]=v0; pr[1]=v1; pr[2]=v2; pr[3]=v3;
}
// poll until all 16 u32 carry tag `want`, then mask tags out
__device__ __forceinline__ void poll_h4(const unsigned int* p, uint4* pr,
                                        unsigned int want){
  for (;;){
    load_h4(p, pr);
    unsigned int diff = 0u;
    #pragma unroll
    for (int b = 0; b < 4; ++b)
      diff |= (pr[b].x ^ want) | (pr[b].y ^ want) | (pr[b].z ^ want) | (pr[b].w ^ want);
    if ((diff & 3u) == 0u) break;
  }
  #pragma unroll
  for (int b = 0; b < 4; ++b){
    pr[b].x &= 0xFFFFFFFCu; pr[b].y &= 0xFFFFFFFCu;
    pr[b].z &= 0xFFFFFFFCu; pr[b].w &= 0xFFFFFFFCu;
  }
}

extern "C" __global__ void __launch_bounds__(NTHREADS, 1)
gru_persistent(const float* __restrict__ hist, const float* __restrict__ wih,
               const float* __restrict__ whh, const float* __restrict__ wpred,
               float* __restrict__ out, unsigned char* __restrict__ ws)
{
  __shared__ __align__(16) unsigned short whi_l[3*16*64*8];   // 49152 B
  __shared__ __align__(16) unsigned short wlo_l[3*16*64*8];   // 49152 B
  __shared__ __align__(16) unsigned short hhi_l[BB*H_DIM];    // 16384 B (swizzled; A rows 0-7, B rows 8-15)
  __shared__ __align__(16) unsigned short hlo_l[BB*H_DIM];    // 16384 B
  __shared__ __align__(16) float part_l[4*3*64*4];            // 12288 B
  __shared__ __align__(16) float x_l[2][BB*I_DIM];            // 1536 B (t&1 double buffer)
  __shared__ __align__(16) float wih_l[48*I_DIM];             // 2304 B
  __shared__ __align__(16) float wpred_l[2*H_DIM];            // 4096 B

  const int tid  = threadIdx.x;
  const int bg   = blockIdx.x & 7;
  const int cg   = blockIdx.x >> 3;
  const int wave = tid >> 6;
  const int lane = tid & 63;
  const int b_log = cg & 15;       // this WG's logit row
  const int o_log = cg >> 4;       // this WG's logit output

  unsigned int* hx[2] = {(unsigned int*)(ws + WS_HX0), (unsigned int*)(ws + WS_HX1)};
  unsigned int* flagsP = (unsigned int*)(ws + WS_FLAGS);

  // ---- Prologue: stage W_ih / W_pred, convert W_hh chunk to LDS fragments ----
  for (int i = tid; i < 48*I_DIM; i += NTHREADS){
    int j = i / I_DIM, ii = i % I_DIM;
    int R = (j >> 4)*H_DIM + cg*HC + (j & 15);      // gate-major rows: r,z,n
    wih_l[i] = wih[R*I_DIM + ii];
  }
  for (int i = tid; i < 2*H_DIM; i += NTHREADS) wpred_l[i] = wpred[i];
  #pragma unroll
  for (int it = 0; it < 24; ++it){
    int f0 = (it*NTHREADS + tid) * 4;               // flat [48*512], k-aligned 4
    int j = f0 >> 9, k = f0 & 511;
    int R = (j >> 4)*H_DIM + cg*HC + (j & 15);
    float4 v = *(const float4*)(whh + R*H_DIM + k);
    int nt = j >> 4;
    int ln = (j & 15) | (((k >> 3) & 3) << 4);
    int kt = k >> 5, e = k & 7;
    int base = (((nt*16 + kt)*64) + ln)*8 + e;      // half index
    float vv[4] = {v.x, v.y, v.z, v.w};
    unsigned short h4[4], l4[4];
    #pragma unroll
    for (int q = 0; q < 4; ++q) split_bf16(vv[q], h4[q], l4[q]);
    uint2 uh, ul;
    uh.x = (unsigned int)h4[0] | ((unsigned int)h4[1] << 16);
    uh.y = (unsigned int)h4[2] | ((unsigned int)h4[3] << 16);
    ul.x = (unsigned int)l4[0] | ((unsigned int)l4[1] << 16);
    ul.y = (unsigned int)l4[2] | ((unsigned int)l4[3] << 16);
    *(uint2*)((char*)whi_l + base*2) = uh;
    *(uint2*)((char*)wlo_l + base*2) = ul;
  }

  // ---- init: rewrite BOTH slots (erase replay-stale tags), then one
  //      sc1 flag barrier (prevents step-0 stale-tag-0 reads). ----
  {
    int b = tid >> 4, hc = tid & 15;
    int gidx = (bg*BB + b)*H_DIM + cg*HC + hc;
    dev_store_u32(hx[0] + gidx, 0u);   // h0=0, tag=0
    dev_store_u32(hx[1] + gidx, 2u);   // payload irrelevant, tag=2
  }
  wait_vm0();
  __syncthreads();
  if (wave == 0 && lane < CG_N)
    dev_store_u32(flagsP + (bg*CG_N + lane)*CG_N + cg, 1u);
  if (wave == 0){
    const unsigned int* fp = flagsP + (bg*CG_N + cg)*CG_N + (lane & 31);
    for (;;){
      unsigned int f = dev_load_u32(fp);
      if (__ballot(f >= 1u) == ~0ull) break;
      __builtin_amdgcn_s_sleep(1);
    }
  }
  __syncthreads();

  // per-thread poll geometry (per half): row = tid&7 (chain-local),
  // cols [(tid>>3)*16, +16) -> 4 dwordx4 chunks
  const int prow = tid & 7;
  const int pc0  = (tid >> 3) * 16;

  // ---- main recurrence: two interleaved chains, 4 raw barriers/step ----
  for (int t = 0; t < T_STEPS; ++t){
    const int cur = t & 1, nxt = cur ^ 1;
    const unsigned int wantT = (unsigned int)(t & 3);

    if (tid < BB*I_DIM){
      int b = tid / I_DIM, ii = tid % I_DIM;
      x_l[cur][tid] = hist[((bg*BB + b)*T_STEPS + t)*I_DIM + ii];
    }

    #pragma unroll
    for (int half = 0; half < 2; ++half){
      const int ro = half * BBH;            // row offset: A=0, B=8
      // Phase 1: poll own chain rows -> unpack -> swizzled LDS rows ro..ro+7
      {
        int lrow = ro + prow;
        const unsigned int* p = hx[cur] + (bg*BB + lrow)*H_DIM + pc0;
        uint4 pr[4];
        poll_h4(p, pr, wantT);
        #pragma unroll
        for (int k = 0; k < 2; ++k){
          uint4 a = pr[2*k], b = pr[2*k+1];
          uint4 hi4 = { hiP(a.x,a.y), hiP(a.z,a.w), hiP(b.x,b.y), hiP(b.z,b.w) };
          uint4 lo4 = { loP(a.x,a.y), loP(a.z,a.w), loP(b.x,b.y), loP(b.z,b.w) };
          int boff = lrow*1024 + (((pc0 + 8*k)*2) ^ ((lrow & 7) << 4));
          *(uint4*)((char*)hhi_l + boff) = hi4;
          *(uint4*)((char*)hlo_l + boff) = lo4;
        }
      }
      bar_lgkm();   // chain tile staged (x_l too, on half 0)

      // Phase 2: GEMM (full 16-row fragments; other chain's rows = ignored garbage)
      f32x4 acc[3];
      #pragma unroll
      for (int nt = 0; nt < 3; ++nt) acc[nt] = {0.f, 0.f, 0.f, 0.f};
      #pragma unroll
      for (int kk = 0; kk < 4; ++kk){
        int kt = wave*4 + kk;
        int arow = lane & 15;
        int aboff = arow*1024 + ((kt*64 + (lane >> 4)*16) ^ ((arow & 7) << 4));
        bf16x8 ahi = *(const bf16x8*)((const char*)hhi_l + aboff);
        bf16x8 alo = *(const bf16x8*)((const char*)hlo_l + aboff);
        #pragma unroll
        for (int nt = 0; nt < 3; ++nt){
          int bboff = (((nt*16 + kt)*64) + lane)*16;
          bf16x8 bhi = *(const bf16x8*)((const char*)whi_l + bboff);
          bf16x8 blo = *(const bf16x8*)((const char*)wlo_l + bboff);
          acc[nt] = MFMA(ahi, bhi, acc[nt]);
          acc[nt] = MFMA(ahi, blo, acc[nt]);
          acc[nt] = MFMA(alo, bhi, acc[nt]);
        }
      }
      #pragma unroll
      for (int nt = 0; nt < 3; ++nt)
        *(f32x4*)(part_l + ((wave*3 + nt)*64 + lane)*4) = acc[nt];
      bar_lgkm();   // partials visible

      // Phase 3: gates + state update + immediate tagged publish (threads 0-127)
      if (tid < BBH*HC){
        int b = ro + (tid >> 4), hc = tid & 15;
        int lc = ((b >> 2) << 4) | hc;
        int rc = b & 3;
        float gh[3];
        #pragma unroll
        for (int g = 0; g < 3; ++g){
          float s = 0.f;
          #pragma unroll
          for (int w = 0; w < 4; ++w) s += part_l[((w*3 + g)*64 + lc)*4 + rc];
          gh[g] = s;
        }
        float gi[3];
        #pragma unroll
        for (int g = 0; g < 3; ++g){
          float s = 0.f;
          #pragma unroll
          for (int ii = 0; ii < I_DIM; ++ii)
            s += x_l[cur][b*I_DIM + ii] * wih_l[(g*16 + hc)*I_DIM + ii];
          gi[g] = s;
        }
        float r = fsigmoid(gi[0] + gh[0]);
        float z = fsigmoid(gi[1] + gh[1]);
        float n = ftanh(gi[2] + r*gh[2]);
        int colg = cg*HC + hc;
        int hoff = b*1024 + ((colg*2) ^ ((b & 7) << 4));
        float hp = bf16f(*(unsigned short*)((char*)hhi_l + hoff))
                 + bf16f(*(unsigned short*)((char*)hlo_l + hoff));
        float hn = (1.0f - z)*n + z*hp;

        unsigned short shi, slo; split_bf16(hn, shi, slo);
        unsigned int pk = ((unsigned int)shi << 16) | ((unsigned int)slo & 0xFFFCu)
                        | (unsigned int)((t + 1) & 3);
        int gidx = (bg*BB + b)*H_DIM + colg;
        dev_store_u32(hx[nxt] + gidx, pk);   // fire and forget — tag rides along
        if (t == T_STEPS - 1) out[32768 + gidx] = hn;   // h_last
      }

      // logits for step t-1 (this WG's row, if it belongs to this chain)
      if (wave == 0 && t > 0 && (b_log >> 3) == half){
        int c = lane * 8;
        int boff = b_log*1024 + ((c*2) ^ ((b_log & 7) << 4));
        uint4 vh = *(const uint4*)((const char*)hhi_l + boff);
        uint4 vl = *(const uint4*)((const char*)hlo_l + boff);
        const unsigned short* ph = (const unsigned short*)&vh;
        const unsigned short* pl = (const unsigned short*)&vl;
        float p = 0.f;
        #pragma unroll
        for (int e = 0; e < 8; ++e)
          p += (bf16f(ph[e]) + bf16f(pl[e])) * wpred_l[o_log*H_DIM + c + e];
        #pragma unroll
        for (int m = 1; m < 64; m <<= 1) p += __shfl_xor(p, m);
        if (lane == 0) out[((bg*BB + b_log)*T_STEPS + (t-1))*2 + o_log] = p;
      }
      // no trailing barrier: next half's post-stage bar orders everything;
      // next same-chain restage is 2 bars away.
    }
  }

  // ---- epilogue: logits for step 127 from hx[0] (tag 128&3 = 0), wave0 ----
  if (wave == 0){
    const unsigned int* p = hx[0] + (bg*BB + b_log)*H_DIM + lane*8;
    uint4 a0, a1;
    for (;;){
      a0 = load4_sc1(p); a1 = load4_sc1(p + 4);
      wait_vm0();
      if (((a0.x | a0.y | a0.z | a0.w | a1.x | a1.y | a1.z | a1.w) & 3u) == 0u) break;
      __builtin_amdgcn_s_sleep(1);
    }
    const unsigned int pk8[8] = {a0.x & 0xFFFFFFFCu, a0.y & 0xFFFFFFFCu,
                                 a0.z & 0xFFFFFFFCu, a0.w & 0xFFFFFFFCu,
                                 a1.x & 0xFFFFFFFCu, a1.y & 0xFFFFFFFCu,
                                 a1.z & 0xFFFFFFFCu, a1.w & 0xFFFFFFFCu};
    float pacc = 0.f;
    #pragma unroll
    for (int e = 0; e < 8; ++e){
      unsigned int v = pk8[e];
      float hv = bf16f((unsigned short)(v >> 16)) + bf16f((unsigned short)(v & 0xFFFFu));
      pacc += hv * wpred_l[o_log*H_DIM + lane*8 + e];
    }
    #pragma unroll
    for (int m = 1; m < 64; m <<= 1) pacc += __shfl_xor(pacc, m);
    if (lane == 0) out[((bg*BB + b_log)*T_STEPS + 127)*2 + o_log] = pacc;
  }
}

extern "C" void kernel_launch(void* const* d_in, const int* in_sizes, int n_in,
                              void* d_out, int out_size, void* d_ws, size_t ws_size,
                              hipStream_t stream) {
  const float* hist  = (const float*)d_in[0];   // [128][128][12]
  const float* wih   = (const float*)d_in[1];   // [1536][12]
  const float* whh   = (const float*)d_in[2];   // [1536][512]
  const float* wpred = (const float*)d_in[3];   // [2][512]
  float* out = (float*)d_out;
  unsigned char* ws = (unsigned char*)d_ws;

  // init-barrier flags must start at 0 every call (sc1 write-through -> reliable)
  hipMemsetAsync(ws + WS_FLAGS, 0, 8*CG_N*CG_N*4, stream);

  gru_persistent<<<dim3(256), dim3(NTHREADS), 0, stream>>>(hist, wih, whh, wpred, out, ws);
}